// Round 16
// baseline (1192.174 us; speedup 1.0000x reference)
//
#include <hip/hip_runtime.h>
#include <hip/hip_bf16.h>
#include <hip/hip_fp16.h>

// Tight stage-1 activations. Per-sample slot = region A + region B (halves).
// A: conv5 out [8cg][70][16][8]=71680. B: conv4-pool out [4cg][72][16][8]=36864.
// conv1/conv2/conv3 outs live in LDS only (fused band kernel).
#define TA 71680
#define SLOT 108544
// conv6 output halves per sample: [8 cg][34 rows][11 cols][8 ci], row stride 11
#define C6N 23936

typedef _Float16 v8h __attribute__((ext_vector_type(8)));
typedef _Float16 v4h __attribute__((ext_vector_type(4)));
typedef float v4f __attribute__((ext_vector_type(4)));
typedef unsigned short u16x8 __attribute__((ext_vector_type(8)));

__device__ inline float h2f(unsigned short u) {
    union { unsigned short s; _Float16 h; } v; v.s = u; return (float)v.h;
}
__device__ inline unsigned short f2h(float f) {
    union { unsigned short s; _Float16 h; } v; v.h = (_Float16)f; return v.s;
}

// ---------------------------------------------------------------------------
// conv1 weight repack into MFMA B-frags for 16x16x16f16, K=16 (taps 0..8
// real, 9..15 ZERO -- the K-pad lives in B so garbage A lanes are harmless).
// frag[(nt*64 + lane)*4 + j]: co = nt*16 + (lane&15), k = (lane>>4)*4 + j.
// ---------------------------------------------------------------------------
__global__ void repack1_k(const float* __restrict__ W, const float* __restrict__ bb,
                          const float* __restrict__ gg, const float* __restrict__ be,
                          const float* __restrict__ mm, const float* __restrict__ vv,
                          unsigned short* __restrict__ frag, float* __restrict__ tOut)
{
    int gid = blockIdx.x * 256 + threadIdx.x;
    if (gid < 32) {
        float s = gg[gid] * rsqrtf(vv[gid] + 1e-5f);
        tOut[gid] = (bb[gid] - mm[gid]) * s + be[gid];
    }
    if (gid >= 512) return;
    int j    = gid & 3;
    int lane = (gid >> 2) & 63;
    int nt   = gid >> 8;
    int k    = (lane >> 4) * 4 + j;
    int co   = nt * 16 + (lane & 15);
    float s = gg[co] * rsqrtf(vv[co] + 1e-5f);
    float w = (k < 9) ? W[co * 9 + k] * s : 0.f;
    frag[gid] = f2h(w);
}

// ---------------------------------------------------------------------------
// MFMA B-fragment repack for 3x3 layers (conv2..conv6), fp16.
// ---------------------------------------------------------------------------
__global__ void repack_mfma_k(const float* __restrict__ W, const float* __restrict__ bb,
                              const float* __restrict__ gg, const float* __restrict__ be,
                              const float* __restrict__ mm, const float* __restrict__ vv,
                              unsigned short* __restrict__ frag, float* __restrict__ tOut,
                              int CIN, int NT, int HALVES)
{
    int gid = blockIdx.x * 256 + threadIdx.x;
    int COUT = NT * 16;
    if (gid < COUT) {
        float s = gg[gid] * rsqrtf(vv[gid] + 1e-5f);
        tOut[gid] = (bb[gid] - mm[gid]) * s + be[gid];
    }
    int tot = 9 * HALVES * NT * 512;
    if (gid >= tot) return;
    int j    = gid & 7;
    int lane = (gid >> 3) & 63;
    int nt   = (gid >> 9) % NT;
    int rest = (gid >> 9) / NT;
    int half = rest % HALVES;
    int khw  = rest / HALVES;
    int ci   = half * 32 + (lane >> 4) * 8 + j;
    int co   = nt * 16 + (lane & 15);
    int kh   = khw / 3, kw = khw % 3;
    float s = gg[co] * rsqrtf(vv[co] + 1e-5f);
    frag[gid] = f2h(W[((co * CIN + ci) * 3 + kh) * 3 + kw] * s);
}

// ---------------------------------------------------------------------------
// Conv7 weight repack into MFMA B-fragment order (12x9 kernel), fp16.
// ---------------------------------------------------------------------------
__global__ void repack7_k(const float* __restrict__ W, const float* __restrict__ bb,
                          const float* __restrict__ gg, const float* __restrict__ be,
                          const float* __restrict__ mm, const float* __restrict__ vv,
                          unsigned short* __restrict__ frag, float* __restrict__ tOut)
{
    int gid = blockIdx.x * 256 + threadIdx.x;
    if (gid < 128) {
        float s = gg[gid] * rsqrtf(vv[gid] + 1e-5f);
        tOut[gid] = (bb[gid] - mm[gid]) * s + be[gid];
    }
    if (gid >= 884736) return;           // 108*2*8*64*8
    int j    = gid & 7;
    int lane = (gid >> 3) & 63;
    int nt   = (gid >> 9) & 7;
    int half = (gid >> 12) & 1;
    int khw  = gid >> 13;
    int co   = nt * 16 + (lane & 15);
    int ci   = half * 32 + (lane >> 4) * 8 + j;
    int kh   = khw / 9, kw = khw - kh * 9;
    float s = gg[co] * rsqrtf(vv[co] + 1e-5f);
    frag[gid] = f2h(W[((co * 64 + ci) * 12 + kh) * 9 + kw] * s);
}

// ---------------------------------------------------------------------------
// FUSED conv1+conv2+conv3+conv4(+pool) per (band, sample).
// Phase 0: stage x-slab as fp16 sxc[19 cols][24 rows] with BOTH pad families
//          baked in: cols {0,1,17,18} = conv SAME pad (always zero), interior
//          zero-filled for T-pad / f-row OOB. + zero s2 halo cols.
// Phase 1: conv1 as MFMA 16x16x16f16 (M=374 slab pos, N=32, K=16 with taps
//          9..15 zeroed in B). A-frag = 4 ds_read_u16 gather (2-way, free).
//          Epilogue zero-stores invalid halo positions (conv2's input halo).
// Phases 2-4: conv2 -> s2 (LDS), conv3 -> s3 (aliases s1), conv4+pool -> B.
// LDS (halves): s1 = 4q x 375c @0 (12000), s2 = 4 x 341c @12000 (10912),
// sxc @22912 (456). Total 23368 h = 46736 B -> 3 blocks/CU.
// ---------------------------------------------------------------------------
__global__ __launch_bounds__(256) void conv1234f_k(
    const float* __restrict__ x, unsigned short* __restrict__ out,
    const unsigned short* __restrict__ f1, const float* __restrict__ t1v,
    const unsigned short* __restrict__ f2, const unsigned short* __restrict__ f3,
    const unsigned short* __restrict__ f4, const float* __restrict__ t2,
    const float* __restrict__ t3, const float* __restrict__ t4, int c0)
{
    __shared__ __align__(16) unsigned short sm[23368];
    unsigned short* sxc = sm + 22912;                    // [19 col][24 row] fp16
    const int band = blockIdx.x;
    const int nl = blockIdx.y;
    const int n = c0 + nl;
    const int tid = threadIdx.x;
    const int wave = tid >> 6, lane = tid & 63;
    const int m = lane & 15, quad = lane >> 4;
    const int b = n / 108, t = n - b * 108;

    // Phase 0: sxc staging + s2 halo zero.
    {
        float4* dst = (float4*)sm;
        for (int i = tid; i < 616; i += 256) {
            if (i < 456) {
                int col2 = i / 24, fp = i - col2 * 24;
                int tt = t - 9 + col2;               // window col c = col2-2
                int ff = band * 16 - 4 + fp;
                float v = 0.f;
                if (col2 >= 2 && col2 <= 16 && tt >= 0 && tt < 108
                    && ff >= 0 && ff < 144)
                    v = x[(b * 108 + tt) * 144 + ff];
                sxc[col2 * 24 + fp] = f2h(v);
            } else {
                int j = i - 456;                 // 4q x 20r x 2cols = 160
                int q = j / 40, jj = j - q * 40;
                int rr = jj >> 1, c2 = (jj & 1) * 16;
                dst[1500 + q * 341 + rr * 17 + c2] = (float4){0.f,0.f,0.f,0.f};
            }
        }
    }
    __syncthreads();

    // Phase 1: conv1 MFMA -> s1 slab [4cg][374 pos][8].
    {
        v4h bf[2];
#pragma unroll
        for (int nt = 0; nt < 2; ++nt)
            bf[nt] = *(const v4h*)(f1 + (nt * 64 + lane) * 4);
        v4f acc1[6][2];
#pragma unroll
        for (int i = 0; i < 6; ++i)
#pragma unroll
            for (int nt = 0; nt < 2; ++nt) acc1[i][nt] = (v4f){0.f,0.f,0.f,0.f};
#pragma unroll
        for (int i = 0; i < 6; ++i) {
            int mtile = wave * 6 + i;
            int p = mtile * 16 + m; if (p > 373) p = 373;
            int r = p / 17, cp = p - r * 17;
            v4h a;
#pragma unroll
            for (int j = 0; j < 4; ++j) {
                int k = quad * 4 + j;
                _Float16 val = (_Float16)0.f;
                if (k < 9) {
                    int kh = k / 3, kw = k - kh * 3;
                    union { unsigned short s; _Float16 h; } cv;
                    cv.s = sxc[(cp + kw) * 24 + (r + kh)];
                    val = cv.h;
                }
                a[j] = val;
            }
#pragma unroll
            for (int nt = 0; nt < 2; ++nt)
                acc1[i][nt] = __builtin_amdgcn_mfma_f32_16x16x16f16(
                    a, bf[nt], acc1[i][nt], 0, 0, 0);
        }
        // Epilogue: store all slab positions (invalid halo -> 0).
#pragma unroll
        for (int i = 0; i < 6; ++i) {
            int mtile = wave * 6 + i;
#pragma unroll
            for (int nt = 0; nt < 2; ++nt) {
                int co = nt * 16 + m;                 // C/D col = lane&15
                float tb = t1v[co];
                unsigned short* ob = sm + (co >> 3) * 3000 + (co & 7);
#pragma unroll
                for (int reg = 0; reg < 4; ++reg) {
                    int p = mtile * 16 + quad * 4 + reg;   // C/D row
                    if (p < 374) {
                        int r = p / 17, cp = p - r * 17;
                        int gr = band * 16 - 3 + r;
                        int gc = cp - 1;
                        bool valid = (gr >= 0 && gr < 144 && gc >= 0 && gc < 15);
                        float val = valid ? fmaxf(acc1[i][nt][reg] + tb, 0.f) : 0.f;
                        ob[p * 8] = f2h(val);
                    }
                }
            }
        }
    }
    __syncthreads();

    v4f acc[2][5];
    int mt[5], la[5];

    // ---------------- conv2: 20 rows x 15 cols = 300 pos, 19 tiles ----------
#pragma unroll
    for (int wt = 0; wt < 5; ++wt) {
        int tt = wave * 5 + wt; if (tt > 18) tt = 18;
        mt[wt] = tt;
        int p = tt * 16 + m; if (p >= 300) p = 299;
        int r = p / 15, c = p - r * 15;
        la[wt] = r * 17 + c;
    }
#pragma unroll
    for (int nt = 0; nt < 2; ++nt)
#pragma unroll
        for (int wt = 0; wt < 5; ++wt) acc[nt][wt] = (v4f){0.f,0.f,0.f,0.f};
#pragma unroll
    for (int khw = 0; khw < 9; ++khw) {
        const int sh = (khw / 3) * 17 + (khw % 3);
        v8h a[5];
#pragma unroll
        for (int wt = 0; wt < 5; ++wt)
            a[wt] = *(const v8h*)(sm + quad * 3000 + (la[wt] + sh) * 8);
#pragma unroll
        for (int nt = 0; nt < 2; ++nt) {
            v8h bb = *(const v8h*)(f2 + (khw * 2 + nt) * 512 + lane * 8);
#pragma unroll
            for (int wt = 0; wt < 5; ++wt)
                acc[nt][wt] = __builtin_amdgcn_mfma_f32_16x16x32_f16(a[wt], bb, acc[nt][wt], 0, 0, 0);
        }
    }
#pragma unroll
    for (int wt = 0; wt < 5; ++wt) {
        const int pb = mt[wt] * 16 + quad * 4;
#pragma unroll
        for (int nt = 0; nt < 2; ++nt) {
            const int co = nt * 16 + m;
            const float tb = t2[co];
            unsigned short* ob = sm + 12000 + (co >> 3) * 2728 + (co & 7);
#pragma unroll
            for (int reg = 0; reg < 4; ++reg) {
                int p = pb + reg;
                if (p < 300) {
                    int r = p / 15, c = p - r * 15;
                    ob[(r * 17 + c + 1) * 8] = f2h(fmaxf(acc[nt][wt][reg] + tb, 0.f));
                }
            }
        }
    }
    __syncthreads();

    // zero s3 halo cols (s3 aliases dead conv1 slab)
    if (tid < 144) {
        int q = tid / 36, jj = tid - q * 36;
        int rr = jj >> 1, c2 = (jj & 1) * 16;
        *(float4*)((float4*)sm + q * 307 + rr * 17 + c2) = (float4){0.f,0.f,0.f,0.f};
    }

    // ---------------- conv3: 18 rows x 15 cols = 270 pos, 17 tiles ----------
#pragma unroll
    for (int wt = 0; wt < 5; ++wt) {
        int tt = wave * 5 + wt; if (tt > 16) tt = 16;
        mt[wt] = tt;
        int p = tt * 16 + m; if (p >= 270) p = 269;
        int r = p / 15, c = p - r * 15;
        la[wt] = r * 17 + c;
    }
#pragma unroll
    for (int nt = 0; nt < 2; ++nt)
#pragma unroll
        for (int wt = 0; wt < 5; ++wt) acc[nt][wt] = (v4f){0.f,0.f,0.f,0.f};
#pragma unroll
    for (int khw = 0; khw < 9; ++khw) {
        const int sh = (khw / 3) * 17 + (khw % 3);
        v8h a[5];
#pragma unroll
        for (int wt = 0; wt < 5; ++wt)
            a[wt] = *(const v8h*)(sm + 12000 + quad * 2728 + (la[wt] + sh) * 8);
#pragma unroll
        for (int nt = 0; nt < 2; ++nt) {
            v8h bb = *(const v8h*)(f3 + (khw * 2 + nt) * 512 + lane * 8);
#pragma unroll
            for (int wt = 0; wt < 5; ++wt)
                acc[nt][wt] = __builtin_amdgcn_mfma_f32_16x16x32_f16(a[wt], bb, acc[nt][wt], 0, 0, 0);
        }
    }
#pragma unroll
    for (int wt = 0; wt < 5; ++wt) {
        const int pb = mt[wt] * 16 + quad * 4;
#pragma unroll
        for (int nt = 0; nt < 2; ++nt) {
            const int co = nt * 16 + m;
            const float tb = t3[co];
            unsigned short* ob = sm + (co >> 3) * 2456 + (co & 7);
#pragma unroll
            for (int reg = 0; reg < 4; ++reg) {
                int p = pb + reg;
                if (p < 270) {
                    int r = p / 15, c = p - r * 15;
                    ob[(r * 17 + c + 1) * 8] = f2h(fmaxf(acc[nt][wt][reg] + tb, 0.f));
                }
            }
        }
    }
    __syncthreads();

    // ---------------- conv4 + pool: 240 pos (pr,w,s ordered), 15 tiles ------
    int mt4[4], la4[4];
#pragma unroll
    for (int wt = 0; wt < 4; ++wt) {
        int tt = wave * 4 + wt; if (tt > 14) tt = 14;
        mt4[wt] = tt;
        int p = tt * 16 + m;
        int pr = p / 30, rem = p - pr * 30;
        int w = rem >> 1, r4 = pr * 2 + (rem & 1);
        la4[wt] = r4 * 17 + w;
    }
    v4f acc4[2][4];
#pragma unroll
    for (int nt = 0; nt < 2; ++nt)
#pragma unroll
        for (int wt = 0; wt < 4; ++wt) acc4[nt][wt] = (v4f){0.f,0.f,0.f,0.f};
#pragma unroll
    for (int khw = 0; khw < 9; ++khw) {
        const int sh = (khw / 3) * 17 + (khw % 3);
        v8h a[4];
#pragma unroll
        for (int wt = 0; wt < 4; ++wt)
            a[wt] = *(const v8h*)(sm + quad * 2456 + (la4[wt] + sh) * 8);
#pragma unroll
        for (int nt = 0; nt < 2; ++nt) {
            v8h bb = *(const v8h*)(f4 + (khw * 2 + nt) * 512 + lane * 8);
#pragma unroll
            for (int wt = 0; wt < 4; ++wt)
                acc4[nt][wt] = __builtin_amdgcn_mfma_f32_16x16x32_f16(a[wt], bb, acc4[nt][wt], 0, 0, 0);
        }
    }
    unsigned short* outN = out + (size_t)nl * SLOT;
#pragma unroll
    for (int wt = 0; wt < 4; ++wt) {
        const int pb = band * 240 + mt4[wt] * 16 + quad * 4;
#pragma unroll
        for (int nt = 0; nt < 2; ++nt) {
            const int co = nt * 16 + m;
            const float tb = t4[co];
            unsigned short* ob = outN + (co >> 3) * 9216 + (co & 7);
#pragma unroll
            for (int pi = 0; pi < 2; ++pi) {
                int pe = pb + pi * 2;
                int pr = pe / 30, rem = pe - pr * 30, w = rem >> 1;
                float v0 = fmaxf(acc4[nt][wt][pi * 2] + tb, 0.f);
                float v1 = fmaxf(acc4[nt][wt][pi * 2 + 1] + tb, 0.f);
                ob[(pr * 16 + w) * 8] = f2h(fmaxf(v0, v1));
            }
        }
    }
}

// ---------------------------------------------------------------------------
// conv5 MFMA: 32->64ch 3x3 VALID, in [4cg][72][16][8] -> out [8cg][70][16][8].
// ---------------------------------------------------------------------------
__global__ __launch_bounds__(256) void conv5m_k(
    const unsigned short* __restrict__ in, unsigned short* __restrict__ out,
    const unsigned short* __restrict__ frag, const float* __restrict__ tv)
{
    const int n = blockIdx.y;
    const int tid = threadIdx.x;
    const int wave = tid >> 6, lane = tid & 63;
    const int m = lane & 15, quad = lane >> 4;
    const unsigned short* inN = in + (size_t)n * SLOT + quad * 9216;

    int mt[2], a0[2];
#pragma unroll
    for (int wt = 0; wt < 2; ++wt) {
        int t = blockIdx.x * 8 + wave * 2 + wt; if (t > 56) t = 56;
        mt[wt] = t;
        int p = t * 16 + m; if (p > 909) p = 909;
        int r = p / 13, w = p - r * 13;
        a0[wt] = (r * 16 + w) * 8;
    }

    v4f acc[4][2];
#pragma unroll
    for (int nt = 0; nt < 4; ++nt)
#pragma unroll
        for (int wt = 0; wt < 2; ++wt) acc[nt][wt] = (v4f){0.f,0.f,0.f,0.f};

#pragma unroll
    for (int khw = 0; khw < 9; ++khw) {
        const int shift = ((khw / 3) * 16 + (khw % 3)) * 8;
        v8h a[2];
#pragma unroll
        for (int wt = 0; wt < 2; ++wt)
            a[wt] = *(const v8h*)(inN + a0[wt] + shift);
#pragma unroll
        for (int nt = 0; nt < 4; ++nt) {
            v8h b = *(const v8h*)(frag + (khw * 4 + nt) * 512 + lane * 8);
#pragma unroll
            for (int wt = 0; wt < 2; ++wt)
                acc[nt][wt] = __builtin_amdgcn_mfma_f32_16x16x32_f16(a[wt], b, acc[nt][wt], 0, 0, 0);
        }
    }

    unsigned short* outN = out + (size_t)n * SLOT;
#pragma unroll
    for (int wt = 0; wt < 2; ++wt) {
        const int pb = mt[wt] * 16 + quad * 4;
#pragma unroll
        for (int nt = 0; nt < 4; ++nt) {
            const int co = nt * 16 + m;
            const float tb = tv[co];
            unsigned short* ob = outN + (co >> 3) * 8960 + (co & 7);
#pragma unroll
            for (int reg = 0; reg < 4; ++reg) {
                int p = pb + reg;
                if (p < 910) {
                    int r = p / 13, w = p - r * 13;
                    ob[(r * 16 + w) * 8] = f2h(fmaxf(acc[nt][wt][reg] + tb, 0.f));
                }
            }
        }
    }
}

// ---------------------------------------------------------------------------
// conv6 MFMA (+fused pool) -> c6 [8cg][34r][11c][8], row stride 11.
// ---------------------------------------------------------------------------
__global__ __launch_bounds__(256) void conv6m_k(
    const unsigned short* __restrict__ in, unsigned short* __restrict__ c6,
    const unsigned short* __restrict__ frag, const float* __restrict__ tv)
{
    const int n = blockIdx.y;
    const int tid = threadIdx.x;
    const int wave = tid >> 6, lane = tid & 63;
    const int m = lane & 15, quad = lane >> 4;
    const unsigned short* inN = in + (size_t)n * SLOT;

    int mt[2], a0[2];
#pragma unroll
    for (int wt = 0; wt < 2; ++wt) {
        int t = blockIdx.x * 8 + wave * 2 + wt; if (t > 46) t = 46;
        mt[wt] = t;
        int p = t * 16 + m; if (p > 747) p = 747;
        int pr = p / 22, rem = p - pr * 22;
        int w = rem >> 1, r = pr * 2 + (rem & 1);
        a0[wt] = (r * 16 + w) * 8;
    }

    v4f acc[4][2];
#pragma unroll
    for (int nt = 0; nt < 4; ++nt)
#pragma unroll
        for (int wt = 0; wt < 2; ++wt) acc[nt][wt] = (v4f){0.f,0.f,0.f,0.f};

#pragma unroll
    for (int khw = 0; khw < 9; ++khw) {
        const int shift = ((khw / 3) * 16 + (khw % 3)) * 8;
#pragma unroll
        for (int half = 0; half < 2; ++half) {
            const unsigned short* ip = inN + (half * 4 + quad) * 8960 + shift;
            v8h a[2];
#pragma unroll
            for (int wt = 0; wt < 2; ++wt)
                a[wt] = *(const v8h*)(ip + a0[wt]);
#pragma unroll
            for (int nt = 0; nt < 4; ++nt) {
                v8h b = *(const v8h*)(frag + ((khw * 2 + half) * 4 + nt) * 512 + lane * 8);
#pragma unroll
                for (int wt = 0; wt < 2; ++wt)
                    acc[nt][wt] = __builtin_amdgcn_mfma_f32_16x16x32_f16(a[wt], b, acc[nt][wt], 0, 0, 0);
            }
        }
    }

    unsigned short* outN = c6 + (size_t)n * C6N;
#pragma unroll
    for (int wt = 0; wt < 2; ++wt) {
        const int pb = mt[wt] * 16 + quad * 4;
#pragma unroll
        for (int nt = 0; nt < 4; ++nt) {
            const int co = nt * 16 + m;
            const float tb = tv[co];
            unsigned short* ob = outN + (co >> 3) * 2992 + (co & 7);
#pragma unroll
            for (int pi = 0; pi < 2; ++pi) {
                int pe = pb + pi * 2;
                if (pe < 748) {
                    int pr = pe / 22, rem = pe - pr * 22, w = rem >> 1;
                    float v0 = fmaxf(acc[nt][wt][pi * 2] + tb, 0.f);
                    float v1 = fmaxf(acc[nt][wt][pi * 2 + 1] + tb, 0.f);
                    ob[(pr * 11 + w) * 8] = f2h(fmaxf(v0, v1));
                }
            }
        }
    }
}

// ---------------------------------------------------------------------------
// Conv7 MFMA GEMM — R12-measured-best config (48 VGPR, 42% occ, 196us):
// LDS 443 quad stride / 13 row stride; staging remaps from stride-11 c6.
// ---------------------------------------------------------------------------
__global__ __launch_bounds__(256) void conv7mfma_k(
    const unsigned short* __restrict__ c6, float* __restrict__ pooled,
    const unsigned short* __restrict__ frag7, const float* __restrict__ tv)
{
    __shared__ __align__(16) unsigned short sA[14176];  // 4 x 443 x 8
    const int n = blockIdx.x;
    const int tid = threadIdx.x;
    const int wave = tid >> 6;
    const int lane = tid & 63;
    const int m = lane & 15;
    const int quad = lane >> 4;

    int pm[5];
#pragma unroll
    for (int mt = 0; mt < 5; ++mt) {
        int p = mt * 16 + m;
        if (p >= 69) p = 0;
        pm[mt] = (p / 3) * 13 + (p % 3);
    }

    v4f acc[2][5];
#pragma unroll
    for (int t = 0; t < 2; ++t)
#pragma unroll
        for (int mt = 0; mt < 5; ++mt)
            acc[t][mt] = (v4f){0.f, 0.f, 0.f, 0.f};

    for (int half = 0; half < 2; ++half) {
        __syncthreads();
        {
            const float4* src = (const float4*)(c6 + (size_t)n * C6N + half * 11968);
            float4* dst = (float4*)sA;
            for (int i = tid; i < 1496; i += 256) {
                int q = i / 374, pos = i - q * 374;
                int h = pos / 11, w = pos - h * 11;
                dst[q * 443 + h * 13 + w] = src[i];
            }
        }
        __syncthreads();
        for (int khw = 0; khw < 108; ++khw) {
            const int off = (khw / 9) * 13 + (khw % 9);
            v8h a[5];
#pragma unroll
            for (int mt = 0; mt < 5; ++mt)
                a[mt] = *(const v8h*)(sA + (quad * 443 + pm[mt] + off) * 8);
            const unsigned short* bp = frag7
                + ((size_t)(khw * 2 + half) * 8) * 512 + lane * 8;
#pragma unroll
            for (int t = 0; t < 2; ++t) {
                const int nt = wave + t * 4;
                v8h b = *(const v8h*)(bp + nt * 512);
#pragma unroll
                for (int mt = 0; mt < 5; ++mt)
                    acc[t][mt] = __builtin_amdgcn_mfma_f32_16x16x32_f16(
                        a[mt], b, acc[t][mt], 0, 0, 0);
            }
        }
    }

    float s[2] = {0.f, 0.f};
#pragma unroll
    for (int t = 0; t < 2; ++t) {
        const float tb = tv[(wave + t * 4) * 16 + m];
#pragma unroll
        for (int mt = 0; mt < 5; ++mt) {
#pragma unroll
            for (int rr = 0; rr < 4; ++rr) {
                int p = mt * 16 + quad * 4 + rr;
                if (p < 69) s[t] += fmaxf(acc[t][mt][rr] + tb, 0.f);
            }
        }
    }
#pragma unroll
    for (int t = 0; t < 2; ++t) {
        s[t] += __shfl_xor(s[t], 16);
        s[t] += __shfl_xor(s[t], 32);
    }
    if (lane < 16) {
#pragma unroll
        for (int t = 0; t < 2; ++t)
            pooled[(size_t)n * 128 + (wave + t * 4) * 16 + lane] = s[t] * (1.f / 69.f);
    }
}

// ---------------------------------------------------------------------------
// logits = b8 + W8(25x128) . pooled
// ---------------------------------------------------------------------------
__global__ void logits_k(const float* __restrict__ pooled, const float* __restrict__ W8,
                         const float* __restrict__ b8, float* __restrict__ outg,
                         int total)
{
    int gid = blockIdx.x * 256 + threadIdx.x;
    if (gid >= total * 25) return;
    int nl = gid / 25, c = gid - nl * 25;
    const float* pp = pooled + (size_t)nl * 128;
    const float* wp = W8 + c * 128;
    float s = b8[c];
#pragma unroll
    for (int ci = 0; ci < 128; ci += 4) {
        float4 wv = *(const float4*)(wp + ci);
        float4 pv = *(const float4*)(pp + ci);
        s = fmaf(wv.x, pv.x, s);
        s = fmaf(wv.y, pv.y, s);
        s = fmaf(wv.z, pv.z, s);
        s = fmaf(wv.w, pv.w, s);
    }
    outg[(size_t)nl * 25 + c] = s;
}

// ---------------------------------------------------------------------------
extern "C" void kernel_launch(void* const* d_in, const int* in_sizes, int n_in,
                              void* d_out, int out_size, void* d_ws, size_t ws_size,
                              hipStream_t stream)
{
    const float* x = (const float*)d_in[0];
    const float* Wl[8]; const float* bl[8]; const float* gl[8];
    const float* bel[8]; const float* ml[8]; const float* vl[8];
    for (int i = 1; i <= 7; ++i) {
        int o = 2 + (i - 1) * 6;
        Wl[i]  = (const float*)d_in[o + 0];
        bl[i]  = (const float*)d_in[o + 1];
        gl[i]  = (const float*)d_in[o + 2];
        bel[i] = (const float*)d_in[o + 3];
        ml[i]  = (const float*)d_in[o + 4];
        vl[i]  = (const float*)d_in[o + 5];
    }
    const float* W8 = (const float*)d_in[44];
    const float* b8 = (const float*)d_in[45];
    float* ws = (float*)d_ws;

    // Workspace layout (float offsets); all 16B aligned.
    unsigned short* f1b = (unsigned short*)(ws + 0);     // 512 h = 256 fl
    float* t1 = ws + 256;                                // 32 fl
    unsigned short* f2b = (unsigned short*)(ws + 320);
    float* t2 = ws + 4928;
    unsigned short* f3b = (unsigned short*)(ws + 4960);
    float* t3 = ws + 9568;
    unsigned short* f4b = (unsigned short*)(ws + 9600);
    float* t4 = ws + 14208;
    unsigned short* f5b = (unsigned short*)(ws + 14240);
    float* t5 = ws + 23456;
    unsigned short* f6b = (unsigned short*)(ws + 23520);
    float* t6 = ws + 41952;
    unsigned short* f7b = (unsigned short*)(ws + 42016);
    float* t7 = ws + 484384;
    const size_t WFL = 484512;

    // Persistent: c6 ([n][8cg][34r][11c][8] fp16) + pooled (fp32).
    unsigned short* c6buf = (unsigned short*)(ws + WFL);
    const size_t C6FL = (size_t)1728 * C6N / 2;
    float* pooled = ws + WFL + C6FL;
    const size_t FIXED = WFL + C6FL + (size_t)1728 * 128;

    size_t avail_fl = ws_size / 4;
    size_t buf_halves = (avail_fl > FIXED) ? (avail_fl - FIXED) * 2 : 0;
    int Cs = (int)(buf_halves / (size_t)SLOT);
    if (Cs < 1) Cs = 1;
    if (Cs > 1728) Cs = 1728;
    unsigned short* bufA = (unsigned short*)(ws + FIXED);   // region A (off 0)
    unsigned short* bufB = bufA + TA;                        // region B (off TA)

    auto g1 = [](int t) { return (t + 255) / 256; };

    // Weight repacks (once per call)
    repack1_k<<<g1(512), 256, 0, stream>>>(Wl[1], bl[1], gl[1], bel[1], ml[1], vl[1], f1b, t1);
    repack_mfma_k<<<g1(9216),  256, 0, stream>>>(Wl[2], bl[2], gl[2], bel[2], ml[2], vl[2], f2b, t2, 32, 2, 1);
    repack_mfma_k<<<g1(9216),  256, 0, stream>>>(Wl[3], bl[3], gl[3], bel[3], ml[3], vl[3], f3b, t3, 32, 2, 1);
    repack_mfma_k<<<g1(9216),  256, 0, stream>>>(Wl[4], bl[4], gl[4], bel[4], ml[4], vl[4], f4b, t4, 32, 2, 1);
    repack_mfma_k<<<g1(18432), 256, 0, stream>>>(Wl[5], bl[5], gl[5], bel[5], ml[5], vl[5], f5b, t5, 32, 4, 1);
    repack_mfma_k<<<g1(36864), 256, 0, stream>>>(Wl[6], bl[6], gl[6], bel[6], ml[6], vl[6], f6b, t6, 64, 4, 2);
    repack7_k<<<g1(884736), 256, 0, stream>>>(Wl[7], bl[7], gl[7], bel[7], ml[7], vl[7], f7b, t7);

    // Stage 1 (chunked, tight layouts):
    // fused conv1/2/3/4 x->B, conv5 B->A, conv6 A->c6
    for (int c0 = 0; c0 < 1728; c0 += Cs) {
        int cn = (1728 - c0 < Cs) ? (1728 - c0) : Cs;
        conv1234f_k<<<dim3(9, cn), 256, 0, stream>>>(x, bufB, f1b, t1,
                                                     f2b, f3b, f4b, t2, t3, t4, c0);
        conv5m_k<<<dim3(8, cn), 256, 0, stream>>>(bufB, bufA, f5b, t5);
        conv6m_k<<<dim3(6, cn), 256, 0, stream>>>(bufA, c6buf + (size_t)c0 * C6N, f6b, t6);
    }

    // Stage 2: conv7 MFMA (+bias+relu+mean) over all samples, then logits.
    conv7mfma_k<<<1728, 256, 0, stream>>>(c6buf, pooled, f7b, t7);
    logits_k<<<g1(1728 * 25), 256, 0, stream>>>(pooled, W8, b8, (float*)d_out, 1728);
}